// Round 6
// baseline (83.131 us; speedup 1.0000x reference)
//
#include <hip/hip_runtime.h>
#include <hip/hip_bf16.h>

// i1e(x) = exp(-|x|) * I1(x), elementwise fp32.
//
// Fast path (|x| <= 8):  i1e(x) = (x/2) * S(x^2/4) * exp(-|x|),
//   S(u) = sum_{k>=0} u^k / (k! (k+1)!)   -- 10-term Horner.
//   Truncation |err| < ~1.2e-5 at |x|=8 (threshold 4.4e-3).
// Cold path (|x| > 8): Cephes asymptotic chbevl(32/z-2, B, 7)/sqrt(z).
//
// Memory: plain (cacheable) loads -- 256 MiB input half-hits L3 across
// replays (measured FETCH 131 MB). Nontemporal stores -- write stream must
// not evict the cached input. One-shot grid, 8x unroll: 8 independent 16B
// loads clustered per thread for deep vmcnt pipelining.

typedef float f32x4 __attribute__((ext_vector_type(4)));

__device__ __forceinline__ float i1e_small(float x) {
    const float z = fabsf(x);
    const float u = (x * x) * 0.25f;
    float s;
    s =       7.5940584e-13f;
    s = fmaf(s, u, 6.8346174e-11f);
    s = fmaf(s, u, 4.9209498e-09f);
    s = fmaf(s, u, 2.7557319e-07f);
    s = fmaf(s, u, 1.1574074e-05f);
    s = fmaf(s, u, 3.4722222e-04f);
    s = fmaf(s, u, 6.9444444e-03f);
    s = fmaf(s, u, 8.3333333e-02f);
    s = fmaf(s, u, 0.5f);
    s = fmaf(s, u, 1.0f);
    const float e = __expf(-z);
    return (0.5f * x) * s * e;   // x carries the sign (I1 is odd)
}

__device__ float i1e_large(float x) {
    const float z = fabsf(x);
    const float w = 32.0f / z - 2.0f;
    float b0 = -3.83538038596423702205E-9f, b1 = 0.0f, b2 = 0.0f;
    const float B[6] = {
        -2.63146884688951950684E-8f,
        -2.51223623787020892529E-7f,
        -3.88256480887769039346E-6f,
        -1.10588938762623716291E-4f,
        -9.76109749136146840777E-3f,
         7.78576235018280120474E-1f
    };
    #pragma unroll
    for (int i = 0; i < 6; ++i) {
        b2 = b1; b1 = b0;
        b0 = w * b1 - b2 + B[i];
    }
    const float r = 0.5f * (b0 - b2) * rsqrtf(z);
    return copysignf(r, x);
}

__device__ __forceinline__ f32x4 i1e_vec4(f32x4 v) {
    f32x4 r;
    r.x = i1e_small(v.x);
    r.y = i1e_small(v.y);
    r.z = i1e_small(v.z);
    r.w = i1e_small(v.w);
    const float m = fmaxf(fmaxf(fabsf(v.x), fabsf(v.y)),
                          fmaxf(fabsf(v.z), fabsf(v.w)));
    if (__builtin_expect(m > 8.0f, 0)) {   // exec-masked cold path, never hit for N(0,1)
        if (fabsf(v.x) > 8.0f) r.x = i1e_large(v.x);
        if (fabsf(v.y) > 8.0f) r.y = i1e_large(v.y);
        if (fabsf(v.z) > 8.0f) r.z = i1e_large(v.z);
        if (fabsf(v.w) > 8.0f) r.w = i1e_large(v.w);
    }
    return r;
}

__global__ void __launch_bounds__(256) Ive_76553497084328_kernel(
        const float* __restrict__ in, float* __restrict__ out, int n) {
    const int n4 = n >> 2;
    const int stride = gridDim.x * blockDim.x;
    const f32x4* __restrict__ in4 = reinterpret_cast<const f32x4*>(in);
    f32x4* __restrict__ out4 = reinterpret_cast<f32x4*>(out);

    int i = blockIdx.x * blockDim.x + threadIdx.x;
    // Grid is sized so this executes exactly once per thread (one-shot);
    // kept as a loop for correctness at any grid size.
    for (; i + 7 * stride < n4; i += 8 * stride) {
        f32x4 v0 = in4[i];
        f32x4 v1 = in4[i + stride];
        f32x4 v2 = in4[i + 2 * stride];
        f32x4 v3 = in4[i + 3 * stride];
        f32x4 v4 = in4[i + 4 * stride];
        f32x4 v5 = in4[i + 5 * stride];
        f32x4 v6 = in4[i + 6 * stride];
        f32x4 v7 = in4[i + 7 * stride];
        f32x4 r0 = i1e_vec4(v0);
        f32x4 r1 = i1e_vec4(v1);
        f32x4 r2 = i1e_vec4(v2);
        f32x4 r3 = i1e_vec4(v3);
        f32x4 r4 = i1e_vec4(v4);
        f32x4 r5 = i1e_vec4(v5);
        f32x4 r6 = i1e_vec4(v6);
        f32x4 r7 = i1e_vec4(v7);
        __builtin_nontemporal_store(r0, &out4[i]);
        __builtin_nontemporal_store(r1, &out4[i + stride]);
        __builtin_nontemporal_store(r2, &out4[i + 2 * stride]);
        __builtin_nontemporal_store(r3, &out4[i + 3 * stride]);
        __builtin_nontemporal_store(r4, &out4[i + 4 * stride]);
        __builtin_nontemporal_store(r5, &out4[i + 5 * stride]);
        __builtin_nontemporal_store(r6, &out4[i + 6 * stride]);
        __builtin_nontemporal_store(r7, &out4[i + 7 * stride]);
    }
    for (; i < n4; i += stride) {
        f32x4 v = in4[i];
        __builtin_nontemporal_store(i1e_vec4(v), &out4[i]);
    }

    // scalar tail (n not divisible by 4)
    const int tail_start = n4 << 2;
    for (int j = tail_start + blockIdx.x * blockDim.x + threadIdx.x; j < n; j += stride) {
        float x = in[j];
        float r = i1e_small(x);
        if (__builtin_expect(fabsf(x) > 8.0f, 0)) r = i1e_large(x);
        out[j] = r;
    }
}

extern "C" void kernel_launch(void* const* d_in, const int* in_sizes, int n_in,
                              void* d_out, int out_size, void* d_ws, size_t ws_size,
                              hipStream_t stream) {
    const float* z = (const float*)d_in[0];
    float* out = (float*)d_out;
    const int n = in_sizes[0];

    const int block = 256;
    const int n4 = n >> 2;
    // One-shot: each thread covers 8 float4 groups.
    long long blocks_ll = ((long long)n4 + (long long)block * 8 - 1) / ((long long)block * 8);
    int blocks = (int)blocks_ll;
    if (blocks < 1) blocks = 1;

    Ive_76553497084328_kernel<<<blocks, block, 0, stream>>>(z, out, n);
}

// Round 7
// 81.124 us; speedup vs baseline: 1.0247x; 1.0247x over previous
//
#include <hip/hip_runtime.h>
#include <hip/hip_bf16.h>

// i1e(x) = exp(-|x|) * I1(x), elementwise fp32.
//
// Fast path (|x| <= 8):  i1e(x) = (x/2) * S(x^2/4) * exp(-|x|),
//   S(u) = sum_{k>=0} u^k / (k! (k+1)!)   -- 10-term Horner.
//   Truncation |err| < ~1.2e-5 at |x|=8 (threshold 4.4e-3).
// Cold path (|x| > 8): Cephes asymptotic chbevl(32/z-2, B, 7)/sqrt(z).
//
// Memory: plain (cacheable) loads -- 256 MiB input half-hits L3 across
// replays (measured FETCH 131 MB vs 262 MB input). Nontemporal stores --
// write stream must not evict the cached input. One-shot grid, 4x unroll
// (best measured: 81.4 us; 8x unroll measured worse at 83.1 us).

typedef float f32x4 __attribute__((ext_vector_type(4)));

__device__ __forceinline__ float i1e_small(float x) {
    const float z = fabsf(x);
    const float u = (x * x) * 0.25f;
    float s;
    s =       7.5940584e-13f;
    s = fmaf(s, u, 6.8346174e-11f);
    s = fmaf(s, u, 4.9209498e-09f);
    s = fmaf(s, u, 2.7557319e-07f);
    s = fmaf(s, u, 1.1574074e-05f);
    s = fmaf(s, u, 3.4722222e-04f);
    s = fmaf(s, u, 6.9444444e-03f);
    s = fmaf(s, u, 8.3333333e-02f);
    s = fmaf(s, u, 0.5f);
    s = fmaf(s, u, 1.0f);
    const float e = __expf(-z);
    return (0.5f * x) * s * e;   // x carries the sign (I1 is odd)
}

__device__ float i1e_large(float x) {
    const float z = fabsf(x);
    const float w = 32.0f / z - 2.0f;
    float b0 = -3.83538038596423702205E-9f, b1 = 0.0f, b2 = 0.0f;
    const float B[6] = {
        -2.63146884688951950684E-8f,
        -2.51223623787020892529E-7f,
        -3.88256480887769039346E-6f,
        -1.10588938762623716291E-4f,
        -9.76109749136146840777E-3f,
         7.78576235018280120474E-1f
    };
    #pragma unroll
    for (int i = 0; i < 6; ++i) {
        b2 = b1; b1 = b0;
        b0 = w * b1 - b2 + B[i];
    }
    const float r = 0.5f * (b0 - b2) * rsqrtf(z);
    return copysignf(r, x);
}

__device__ __forceinline__ f32x4 i1e_vec4(f32x4 v) {
    f32x4 r;
    r.x = i1e_small(v.x);
    r.y = i1e_small(v.y);
    r.z = i1e_small(v.z);
    r.w = i1e_small(v.w);
    const float m = fmaxf(fmaxf(fabsf(v.x), fabsf(v.y)),
                          fmaxf(fabsf(v.z), fabsf(v.w)));
    if (__builtin_expect(m > 8.0f, 0)) {   // exec-masked cold path, never hit for N(0,1)
        if (fabsf(v.x) > 8.0f) r.x = i1e_large(v.x);
        if (fabsf(v.y) > 8.0f) r.y = i1e_large(v.y);
        if (fabsf(v.z) > 8.0f) r.z = i1e_large(v.z);
        if (fabsf(v.w) > 8.0f) r.w = i1e_large(v.w);
    }
    return r;
}

__global__ void __launch_bounds__(256) Ive_76553497084328_kernel(
        const float* __restrict__ in, float* __restrict__ out, int n) {
    const int n4 = n >> 2;
    const int stride = gridDim.x * blockDim.x;
    const f32x4* __restrict__ in4 = reinterpret_cast<const f32x4*>(in);
    f32x4* __restrict__ out4 = reinterpret_cast<f32x4*>(out);

    int i = blockIdx.x * blockDim.x + threadIdx.x;
    // Grid is sized so this executes exactly once per thread (one-shot);
    // kept as a loop for correctness at any grid size.
    for (; i + 3 * stride < n4; i += 4 * stride) {
        f32x4 v0 = in4[i];
        f32x4 v1 = in4[i + stride];
        f32x4 v2 = in4[i + 2 * stride];
        f32x4 v3 = in4[i + 3 * stride];
        f32x4 r0 = i1e_vec4(v0);
        f32x4 r1 = i1e_vec4(v1);
        f32x4 r2 = i1e_vec4(v2);
        f32x4 r3 = i1e_vec4(v3);
        __builtin_nontemporal_store(r0, &out4[i]);
        __builtin_nontemporal_store(r1, &out4[i + stride]);
        __builtin_nontemporal_store(r2, &out4[i + 2 * stride]);
        __builtin_nontemporal_store(r3, &out4[i + 3 * stride]);
    }
    for (; i < n4; i += stride) {
        f32x4 v = in4[i];
        __builtin_nontemporal_store(i1e_vec4(v), &out4[i]);
    }

    // scalar tail (n not divisible by 4)
    const int tail_start = n4 << 2;
    for (int j = tail_start + blockIdx.x * blockDim.x + threadIdx.x; j < n; j += stride) {
        float x = in[j];
        float r = i1e_small(x);
        if (__builtin_expect(fabsf(x) > 8.0f, 0)) r = i1e_large(x);
        out[j] = r;
    }
}

extern "C" void kernel_launch(void* const* d_in, const int* in_sizes, int n_in,
                              void* d_out, int out_size, void* d_ws, size_t ws_size,
                              hipStream_t stream) {
    const float* z = (const float*)d_in[0];
    float* out = (float*)d_out;
    const int n = in_sizes[0];

    const int block = 256;
    const int n4 = n >> 2;
    // One-shot: each thread covers 4 float4 groups.
    long long blocks_ll = ((long long)n4 + (long long)block * 4 - 1) / ((long long)block * 4);
    int blocks = (int)blocks_ll;
    if (blocks < 1) blocks = 1;

    Ive_76553497084328_kernel<<<blocks, block, 0, stream>>>(z, out, n);
}